// Round 6
// baseline (102.297 us; speedup 1.0000x reference)
//
#include <hip/hip_runtime.h>
#include <hip/hip_bf16.h>
#include <stdint.h>

// SelfAttention: B=8, C=64, N=4096, d_k=8.
// out[b,c,m] = gamma * (sum_n h[b,c,n] * softmax_n(f[:,n].g[:,m])) + x[b,c,m]
//
// R6: attn re-partitioned for occupancy. R5 post-mortem: latency-bound at
// 2 waves/SIMD; native mfma shortened a non-binding chain. Now 512-thread
// blocks, 8 waves = (m-tile, n-quarter) pairs -> 4 waves/SIMD with per-wave
// state ~100 VGPR (fits the __launch_bounds__(512,4) 128-VGPR cap; R4's
// failure was 2 m-tiles/wave at a 64-VGPR cap).
//   QK: native 32x32x16, K padded 8->16 (qf zeroed in hh=1 lanes).
//   tau row-permute (l5^12 on groups 4-7<->8-11, 20-23<->24-27) makes
//   S^T regs 0..7 / 8..15 pack sequentially into PV A-frags (zero shuffles).
//   PV: 4 native mfma per 32-n iter.
// hswz (V) layout per 32-n tile (4096 B), 32x32x16 B-frag order:
//   offset = chunk*2048 + ct*1024 + (hh*32+l5)*16 holding
//   h[c=ct*32+l5][n = nb*32 + chunk*16 + 8*hh + j], j=0..7.
// K1 (fgh): unchanged MFMA projection (x read once, ~HBM floor).

typedef short v4s __attribute__((ext_vector_type(4)));
typedef short v8s __attribute__((ext_vector_type(8)));
typedef float v16f __attribute__((ext_vector_type(16)));
typedef unsigned int v4u __attribute__((ext_vector_type(4)));
typedef unsigned int v2u __attribute__((ext_vector_type(2)));

__device__ __forceinline__ unsigned bf16pair(float lo, float hi) {
    unsigned a = __builtin_bit_cast(unsigned, lo) + 0x8000u;
    unsigned b = __builtin_bit_cast(unsigned, hi) + 0x8000u;
    return (a >> 16) | (b & 0xffff0000u);
}
__device__ __forceinline__ unsigned short bf16r(float x) {
    return (unsigned short)((__builtin_bit_cast(unsigned, x) + 0x8000u) >> 16);
}
// truncating bf16 pack via v_perm: dword = [hi16(hi) | hi16(lo)]
__device__ __forceinline__ unsigned packt(float lo, float hi) {
    return __builtin_amdgcn_perm(__builtin_bit_cast(unsigned, hi),
                                 __builtin_bit_cast(unsigned, lo), 0x07060302u);
}

// ---------------- K1: MFMA projection ----------------
// grid 1024 = (b<<7)|nb. Wave w<2: h rows w*32..+31; wave 2: f(0-7)+g(8-15).
__global__ __launch_bounds__(256) void fgh_kernel(
    const float* __restrict__ x, const float* __restrict__ Wq,
    const float* __restrict__ Wk, const float* __restrict__ Wv,
    unsigned int* __restrict__ ftgt,   // ft dwords [0,131072), gt [131072,262144)
    v4u* __restrict__ hswz)
{
    __shared__ v2u wfrag[1536];        // 3 row-groups x 8 kb x 64 lanes x 8B
    __shared__ v2u xfrag[512];         // 8 kb x 64 lanes x 8B
    __shared__ short hbuf[64 * 36];    // [c][nloc] pad 36 (72B rows, 8B-aligned)

    const int blk  = blockIdx.x;
    const int b    = blk >> 7;
    const int nb   = blk & 127;
    const int n0   = nb << 5;
    const int tid  = threadIdx.x;
    const int wave = tid >> 6;
    const int lane = tid & 63;
    const int l5   = lane & 31;
    const int hh   = lane >> 5;

    const float* xb = x + (size_t)b * 262144 + n0;

    // stage W fragments: A[row][k=kb*8+4*hf+j] (legacy frag; negligible mfma count)
    #pragma unroll
    for (int i = 0; i < 6; ++i) {
        const int e  = tid + i * 256;
        const int w  = e >> 9;
        const int kb = (e >> 6) & 7;
        const int r  = e & 31;
        const int hf = (e >> 5) & 1;
        const int k0 = kb * 8 + hf * 4;
        float4 wv = make_float4(0.f, 0.f, 0.f, 0.f);
        if (w == 0)      wv = *(const float4*)(Wv + r * 64 + k0);
        else if (w == 1) wv = *(const float4*)(Wv + (32 + r) * 64 + k0);
        else if (r < 8)  wv = *(const float4*)(Wq + r * 64 + k0);
        else if (r < 16) {
            wv = *(const float4*)(Wk + (r - 8) * 64 + k0);
            const float s = 1.4426950408889634f;   // fold log2(e) into g
            wv.x *= s; wv.y *= s; wv.z *= s; wv.w *= s;
        }
        v2u d; d.x = bf16pair(wv.x, wv.y); d.y = bf16pair(wv.z, wv.w);
        wfrag[e] = d;
    }

    // stage x fragments: B[col=n][k=c]
    #pragma unroll
    for (int i = 0; i < 2; ++i) {
        const int e  = tid + i * 256;
        const int kb = e >> 6;
        const int nn = e & 31;
        const int hf = (e >> 5) & 1;
        const int c0 = kb * 8 + hf * 4;
        const float a0 = xb[(size_t)(c0 + 0) * 4096 + nn];
        const float a1 = xb[(size_t)(c0 + 1) * 4096 + nn];
        const float a2 = xb[(size_t)(c0 + 2) * 4096 + nn];
        const float a3 = xb[(size_t)(c0 + 3) * 4096 + nn];
        v2u d; d.x = bf16pair(a0, a1); d.y = bf16pair(a2, a3);
        xfrag[e] = d;
    }
    __syncthreads();

    if (wave < 3) {
        v16f dacc = {0.f,0.f,0.f,0.f,0.f,0.f,0.f,0.f,0.f,0.f,0.f,0.f,0.f,0.f,0.f,0.f};
        #pragma unroll
        for (int kb = 0; kb < 8; ++kb) {
            const v4s af = __builtin_bit_cast(v4s, wfrag[wave * 512 + kb * 64 + lane]);
            const v4s bf = __builtin_bit_cast(v4s, xfrag[kb * 64 + lane]);
            dacc = __builtin_amdgcn_mfma_f32_32x32x8bf16_1k(af, bf, dacc, 0, 0, 0);
        }
        // D: row=(r&3)+8*(r>>2)+4*hh, col=n0+l5
        if (wave < 2) {
            #pragma unroll
            for (int r = 0; r < 16; ++r) {
                const int rowD = (r & 3) + ((r >> 2) << 3) + (hh << 2);
                hbuf[(wave * 32 + rowD) * 36 + l5] = (short)bf16r(dacc[r]);
            }
        } else {
            const size_t nidx = (size_t)b * 4096 + n0 + l5;
            v2u f; f.x = bf16pair(dacc[0], dacc[1]); f.y = bf16pair(dacc[2], dacc[3]);
            v2u g; g.x = bf16pair(dacc[4], dacc[5]); g.y = bf16pair(dacc[6], dacc[7]);
            *(v2u*)(ftgt + nidx * 4 + hh * 2) = f;
            *(v2u*)(ftgt + 131072 + nidx * 4 + hh * 2) = g;
        }
    }
    __syncthreads();

    // assemble hswz for 32x32x16 B-frag: thread t emits 16 contiguous bytes:
    // t = chunk*128 + ct*64 + hh2*32 + lp -> h[c=ct*32+lp][n=chunk*16+hh2*8+j]
    const int chunk = tid >> 7;
    const int ct    = (tid >> 6) & 1;
    const int hh2   = (tid >> 5) & 1;
    const int lp    = tid & 31;
    const short* src = hbuf + (ct * 32 + lp) * 36 + chunk * 16 + hh2 * 8;
    const v2u lo = *(const v2u*)(src);
    const v2u hi = *(const v2u*)(src + 4);
    v4u o; o.x = lo.x; o.y = lo.y; o.z = hi.x; o.w = hi.y;
    hswz[(size_t)(b * 128 + nb) * 256 + tid] = o;
}

// ---------------- K2: fused attention (native 32x32x16 MFMA) ----------------
// grid 512 = (b<<6)|mb, m0 = mb*64. 8 waves: wave = (tile = w>>2, q = w&3);
// wave does m-tile [m0+32*tile, +32) x n in [q*1024, +1024).
__global__ __launch_bounds__(512, 4) void attn_kernel(
    const v4u* __restrict__ ft16,     // [b][n] 16B rows (8 bf16)
    const v4u* __restrict__ gt16,
    const char* __restrict__ hswz,
    const float* __restrict__ x,
    const float* __restrict__ gamma,
    float* __restrict__ out)
{
    __shared__ float ldsO[2][2][32 * 65];   // [tile][copy][m][c] (pad 65)
    __shared__ float ldsL[2][2][32];

    const int blk  = blockIdx.x;
    const int b    = blk >> 6;
    const int m0   = (blk & 63) << 6;
    const int tid  = threadIdx.x;
    const int wave = tid >> 6;
    const int tile = wave >> 2;
    const int q    = wave & 3;
    const int lane = tid & 63;
    const int l5   = lane & 31;
    const int hh   = lane >> 5;

    // tau: swap row-groups 4-7<->8-11 and 20-23<->24-27 (loop-invariant)
    int krow = l5;
    if (((l5 >> 2) ^ (l5 >> 3)) & 1) krow = l5 ^ 12;

    // Q B-frag: col m = m0+32*tile+l5, k=8*hh+j. hh=1 half is K-padding -> 0.
    v8s qf = __builtin_bit_cast(v8s, gt16[(size_t)b * 4096 + m0 + tile * 32 + l5]);
    if (hh) qf = (v8s)0;

    v16f acc0 = {0.f,0.f,0.f,0.f,0.f,0.f,0.f,0.f,0.f,0.f,0.f,0.f,0.f,0.f,0.f,0.f};
    v16f acc1 = acc0;
    float lsum = 0.f;

    const char* vb = hswz + (size_t)b * 524288 + lane * 16;
    const int nbase = q << 10;

    // prefetch iter 0
    v4u kf_n = ft16[(size_t)b * 4096 + nbase + krow];
    v4u vv_n[4];
    #pragma unroll
    for (int qq = 0; qq < 4; ++qq)
        vv_n[qq] = *(const v4u*)(vb + (size_t)(nbase >> 5) * 4096 + qq * 1024);

    for (int it = 0; it < 32; ++it) {
        const v8s kf = __builtin_bit_cast(v8s, kf_n);
        v4u vv[4];
        #pragma unroll
        for (int qq = 0; qq < 4; ++qq) vv[qq] = vv_n[qq];

        const int itn = (it + 1) & 31;            // wrap: valid, unused
        const int n0n = nbase + (itn << 5);
        kf_n = ft16[(size_t)b * 4096 + n0n + krow];
        #pragma unroll
        for (int qq = 0; qq < 4; ++qq)
            vv_n[qq] = *(const v4u*)(vb + (size_t)(n0n >> 5) * 4096 + qq * 1024);

        v16f z = {0.f,0.f,0.f,0.f,0.f,0.f,0.f,0.f,0.f,0.f,0.f,0.f,0.f,0.f,0.f,0.f};
        v16f s = __builtin_amdgcn_mfma_f32_32x32x16_bf16(kf, qf, z, 0, 0, 0);
        // after tau: s[0..7] = P(n_local=8hh+reg), s[8..15] = n_local 16..31
        // -> sequential pack = 32x32x16 A-operand layout.

        float p[16];
        #pragma unroll
        for (int j = 0; j < 16; ++j) p[j] = __builtin_amdgcn_exp2f(s[j]);
        #pragma unroll
        for (int j = 0; j < 16; ++j) lsum += p[j];

        v4u a0, a1;
        a0.x = packt(p[0], p[1]);   a0.y = packt(p[2], p[3]);
        a0.z = packt(p[4], p[5]);   a0.w = packt(p[6], p[7]);
        a1.x = packt(p[8], p[9]);   a1.y = packt(p[10], p[11]);
        a1.z = packt(p[12], p[13]); a1.w = packt(p[14], p[15]);

        const v8s pA0 = __builtin_bit_cast(v8s, a0);    // n 0-15
        const v8s pA1 = __builtin_bit_cast(v8s, a1);    // n 16-31
        const v8s V00 = __builtin_bit_cast(v8s, vv[0]); // n 0-15,  c 0-31
        const v8s V01 = __builtin_bit_cast(v8s, vv[1]); // n 0-15,  c 32-63
        const v8s V10 = __builtin_bit_cast(v8s, vv[2]); // n 16-31, c 0-31
        const v8s V11 = __builtin_bit_cast(v8s, vv[3]); // n 16-31, c 32-63

        acc0 = __builtin_amdgcn_mfma_f32_32x32x16_bf16(pA0, V00, acc0, 0, 0, 0);
        acc1 = __builtin_amdgcn_mfma_f32_32x32x16_bf16(pA0, V01, acc1, 0, 0, 0);
        acc0 = __builtin_amdgcn_mfma_f32_32x32x16_bf16(pA1, V10, acc0, 0, 0, 0);
        acc1 = __builtin_amdgcn_mfma_f32_32x32x16_bf16(pA1, V11, acc1, 0, 0, 0);
    }

    // fold lane/lane+32 (same m, disjoint n)
    lsum += __shfl_xor(lsum, 32);

    // per-tile 2-copy write-then-add combine
    if (q < 2) {
        float* P = &ldsO[tile][q][0];
        #pragma unroll
        for (int r = 0; r < 16; ++r) {
            const int rowD = (r & 3) + ((r >> 2) << 3) + (hh << 2);
            P[rowD * 65 + l5]      = acc0[r];
            P[rowD * 65 + 32 + l5] = acc1[r];
        }
        if (hh == 0) ldsL[tile][q][l5] = lsum;
    }
    __syncthreads();
    if (q >= 2) {
        float* P = &ldsO[tile][q - 2][0];
        #pragma unroll
        for (int r = 0; r < 16; ++r) {
            const int rowD = (r & 3) + ((r >> 2) << 3) + (hh << 2);
            P[rowD * 65 + l5]      += acc0[r];
            P[rowD * 65 + 32 + l5] += acc1[r];
        }
        if (hh == 0) ldsL[tile][q - 2][l5] += lsum;
    }
    __syncthreads();

    // final: normalize + gamma*o + x, coalesced over m (64 consecutive)
    const float gam = gamma[0];
    const int m    = tid & 63;
    const int mt   = m >> 5;
    const int ml   = m & 31;
    const int c0   = (tid >> 6) * 8;
    const float L  = ldsL[mt][0][ml] + ldsL[mt][1][ml];
    const float rL = 1.0f / L;
    #pragma unroll
    for (int k = 0; k < 8; ++k) {
        const int c = c0 + k;
        const float O = ldsO[mt][0][ml * 65 + c] + ldsO[mt][1][ml * 65 + c];
        const size_t idx = ((size_t)b * 64 + c) * 4096 + m0 + m;
        out[idx] = gam * (O * rL) + x[idx];
    }
}

extern "C" void kernel_launch(void* const* d_in, const int* in_sizes, int n_in,
                              void* d_out, int out_size, void* d_ws, size_t ws_size,
                              hipStream_t stream) {
    const float* x     = (const float*)d_in[0];
    const float* Wq    = (const float*)d_in[1];
    const float* Wk    = (const float*)d_in[2];
    const float* Wv    = (const float*)d_in[3];
    const float* gamma = (const float*)d_in[4];
    float* out = (float*)d_out;

    unsigned int* ftgt = (unsigned int*)d_ws;   // ft 512KB + gt 512KB
    v4u* hswz = (v4u*)(ftgt + 262144);          // 4MB fragment-swizzled h

    hipLaunchKernelGGL(fgh_kernel, dim3(1024), dim3(256), 0, stream,
                       x, Wq, Wk, Wv, ftgt, hswz);
    hipLaunchKernelGGL(attn_kernel, dim3(512), dim3(512), 0, stream,
                       (const v4u*)ftgt, (const v4u*)(ftgt + 131072),
                       (const char*)hswz, x, gamma, out);
}

// Round 7
// 98.926 us; speedup vs baseline: 1.0341x; 1.0341x over previous
//
#include <hip/hip_runtime.h>
#include <hip/hip_bf16.h>
#include <stdint.h>

// SelfAttention: B=8, C=64, N=4096, d_k=8.
// out[b,c,m] = gamma * (sum_n h[b,c,n] * softmax_n(f[:,n].g[:,m])) + x[b,c,m]
//
// R7: attn is L1/vector-return-path bound (R3/R5/R6 all ~41us regardless of
// occupancy & mfma rate; per-CU global V traffic 2.5 MB was the invariant).
// Now: grid 256 (1 block/CU), 1024 thr = 16 waves = 4 m-tiles x 4 n-quarters,
// V+K staged through double-buffered LDS (one barrier/step, 32 steps of 32-n
// per quarter). V read once per block: per-CU global bytes 2.5 MB -> 0.55 MB.
//   QK: native 32x32x16, K padded 8->16 (qf zeroed in hh=1 lanes).
//   tau row-permute (l5^12 on groups 4-7<->8-11, 20-23<->24-27) on the K row
//   makes S^T regs 0..7/8..15 pack sequentially into PV A-frags (no shuffles).
// hswz (V) layout per 32-n tile (4096 B), 32x32x16 B-frag order:
//   offset = chunk*2048 + ct*1024 + (hh*32+l5)*16 holding
//   h[c=ct*32+l5][n = nb*32 + chunk*16 + 8*hh + j], j=0..7.
// K1 (fgh): unchanged MFMA projection (x read once, ~HBM floor).

typedef short v4s __attribute__((ext_vector_type(4)));
typedef short v8s __attribute__((ext_vector_type(8)));
typedef float v16f __attribute__((ext_vector_type(16)));
typedef unsigned int v4u __attribute__((ext_vector_type(4)));
typedef unsigned int v2u __attribute__((ext_vector_type(2)));

__device__ __forceinline__ unsigned bf16pair(float lo, float hi) {
    unsigned a = __builtin_bit_cast(unsigned, lo) + 0x8000u;
    unsigned b = __builtin_bit_cast(unsigned, hi) + 0x8000u;
    return (a >> 16) | (b & 0xffff0000u);
}
__device__ __forceinline__ unsigned short bf16r(float x) {
    return (unsigned short)((__builtin_bit_cast(unsigned, x) + 0x8000u) >> 16);
}
// truncating bf16 pack via v_perm: dword = [hi16(hi) | hi16(lo)]
__device__ __forceinline__ unsigned packt(float lo, float hi) {
    return __builtin_amdgcn_perm(__builtin_bit_cast(unsigned, hi),
                                 __builtin_bit_cast(unsigned, lo), 0x07060302u);
}

// ---------------- K1: MFMA projection ----------------
// grid 1024 = (b<<7)|nb. Wave w<2: h rows w*32..+31; wave 2: f(0-7)+g(8-15).
__global__ __launch_bounds__(256) void fgh_kernel(
    const float* __restrict__ x, const float* __restrict__ Wq,
    const float* __restrict__ Wk, const float* __restrict__ Wv,
    unsigned int* __restrict__ ftgt,   // ft dwords [0,131072), gt [131072,262144)
    v4u* __restrict__ hswz)
{
    __shared__ v2u wfrag[1536];        // 3 row-groups x 8 kb x 64 lanes x 8B
    __shared__ v2u xfrag[512];         // 8 kb x 64 lanes x 8B
    __shared__ short hbuf[64 * 36];    // [c][nloc] pad 36 (72B rows, 8B-aligned)

    const int blk  = blockIdx.x;
    const int b    = blk >> 7;
    const int nb   = blk & 127;
    const int n0   = nb << 5;
    const int tid  = threadIdx.x;
    const int wave = tid >> 6;
    const int lane = tid & 63;
    const int l5   = lane & 31;
    const int hh   = lane >> 5;

    const float* xb = x + (size_t)b * 262144 + n0;

    // stage W fragments: A[row][k=kb*8+4*hf+j] (legacy frag; negligible count)
    #pragma unroll
    for (int i = 0; i < 6; ++i) {
        const int e  = tid + i * 256;
        const int w  = e >> 9;
        const int kb = (e >> 6) & 7;
        const int r  = e & 31;
        const int hf = (e >> 5) & 1;
        const int k0 = kb * 8 + hf * 4;
        float4 wv = make_float4(0.f, 0.f, 0.f, 0.f);
        if (w == 0)      wv = *(const float4*)(Wv + r * 64 + k0);
        else if (w == 1) wv = *(const float4*)(Wv + (32 + r) * 64 + k0);
        else if (r < 8)  wv = *(const float4*)(Wq + r * 64 + k0);
        else if (r < 16) {
            wv = *(const float4*)(Wk + (r - 8) * 64 + k0);
            const float s = 1.4426950408889634f;   // fold log2(e) into g
            wv.x *= s; wv.y *= s; wv.z *= s; wv.w *= s;
        }
        v2u d; d.x = bf16pair(wv.x, wv.y); d.y = bf16pair(wv.z, wv.w);
        wfrag[e] = d;
    }

    // stage x fragments: B[col=n][k=c]
    #pragma unroll
    for (int i = 0; i < 2; ++i) {
        const int e  = tid + i * 256;
        const int kb = e >> 6;
        const int nn = e & 31;
        const int hf = (e >> 5) & 1;
        const int c0 = kb * 8 + hf * 4;
        const float a0 = xb[(size_t)(c0 + 0) * 4096 + nn];
        const float a1 = xb[(size_t)(c0 + 1) * 4096 + nn];
        const float a2 = xb[(size_t)(c0 + 2) * 4096 + nn];
        const float a3 = xb[(size_t)(c0 + 3) * 4096 + nn];
        v2u d; d.x = bf16pair(a0, a1); d.y = bf16pair(a2, a3);
        xfrag[e] = d;
    }
    __syncthreads();

    if (wave < 3) {
        v16f dacc = {0.f,0.f,0.f,0.f,0.f,0.f,0.f,0.f,0.f,0.f,0.f,0.f,0.f,0.f,0.f,0.f};
        #pragma unroll
        for (int kb = 0; kb < 8; ++kb) {
            const v4s af = __builtin_bit_cast(v4s, wfrag[wave * 512 + kb * 64 + lane]);
            const v4s bf = __builtin_bit_cast(v4s, xfrag[kb * 64 + lane]);
            dacc = __builtin_amdgcn_mfma_f32_32x32x8bf16_1k(af, bf, dacc, 0, 0, 0);
        }
        // D: row=(r&3)+8*(r>>2)+4*hh, col=n0+l5
        if (wave < 2) {
            #pragma unroll
            for (int r = 0; r < 16; ++r) {
                const int rowD = (r & 3) + ((r >> 2) << 3) + (hh << 2);
                hbuf[(wave * 32 + rowD) * 36 + l5] = (short)bf16r(dacc[r]);
            }
        } else {
            const size_t nidx = (size_t)b * 4096 + n0 + l5;
            v2u f; f.x = bf16pair(dacc[0], dacc[1]); f.y = bf16pair(dacc[2], dacc[3]);
            v2u g; g.x = bf16pair(dacc[4], dacc[5]); g.y = bf16pair(dacc[6], dacc[7]);
            *(v2u*)(ftgt + nidx * 4 + hh * 2) = f;
            *(v2u*)(ftgt + 131072 + nidx * 4 + hh * 2) = g;
        }
    }
    __syncthreads();

    // assemble hswz: t = chunk*128 + ct*64 + hh2*32 + lp ->
    // h[c=ct*32+lp][n=chunk*16+hh2*8+j], 16 contiguous bytes
    const int chunk = tid >> 7;
    const int ct    = (tid >> 6) & 1;
    const int hh2   = (tid >> 5) & 1;
    const int lp    = tid & 31;
    const short* src = hbuf + (ct * 32 + lp) * 36 + chunk * 16 + hh2 * 8;
    const v2u lo = *(const v2u*)(src);
    const v2u hi = *(const v2u*)(src + 4);
    v4u o; o.x = lo.x; o.y = lo.y; o.z = hi.x; o.w = hi.y;
    hswz[(size_t)(b * 128 + nb) * 256 + tid] = o;
}

// ---------------- K2: fused attention, LDS-staged ----------------
// grid 256 = (b<<5)|mc, m0 = mc*128. 16 waves: tile = w>>2, q = w&3.
// Wave (t,q): m-tile [m0+32t, +32) x n-quarter [q*1024, +1024), 32 steps x 32n.
__global__ __launch_bounds__(1024) void attn_kernel(
    const v4u* __restrict__ ft16,     // [b][n] 16B rows (8 bf16)
    const v4u* __restrict__ gt16,
    const char* __restrict__ hswz,
    const float* __restrict__ x,
    const float* __restrict__ gamma,
    float* __restrict__ out)
{
    // staging: V bufs 2x16KB at 0; kf bufs 2x2KB at 32768. epilogue aliases.
    __shared__ char smem[36864];
    float* ldsO = (float*)smem;              // [128 m][65] = 33280 B
    float* ldsL = (float*)(smem + 33280);    // [128 m]

    const int blk  = blockIdx.x;
    const int b    = blk >> 5;
    const int m0   = (blk & 31) << 7;
    const int tid  = threadIdx.x;
    const int wave = tid >> 6;
    const int tile = wave >> 2;
    const int q    = wave & 3;
    const int lane = tid & 63;
    const int l5   = lane & 31;
    const int hh   = lane >> 5;

    // tau: swap row-groups 4-7<->8-11 and 20-23<->24-27 (loop-invariant)
    int krow = l5;
    if (((l5 >> 2) ^ (l5 >> 3)) & 1) krow = l5 ^ 12;

    // Q B-frag: col m = m0+32*tile+l5, k=8*hh+j. hh=1 half is K-padding -> 0.
    v8s qf = __builtin_bit_cast(v8s, gt16[(size_t)b * 4096 + m0 + tile * 32 + l5]);
    if (hh) qf = (v8s)0;

    v16f acc0 = {0.f,0.f,0.f,0.f,0.f,0.f,0.f,0.f,0.f,0.f,0.f,0.f,0.f,0.f,0.f,0.f};
    v16f acc1 = acc0;
    float lsum = 0.f;

    // staging maps (thread-flat, wave-role-independent)
    const char* hv = hswz + (size_t)b * 524288;
    const int sq   = tid >> 8;           // V: quarter this thread stages
    const int soff = (tid & 255) * 16;   // 4 KB per quarter-step
    const int kq   = tid >> 5;           // kf: threads 0-127
    const int krw  = tid & 31;

    v4u Vreg, Kreg;
    // prologue: stage step 0 into buf 0
    Vreg = *(const v4u*)(hv + (size_t)(sq * 32 + 0) * 4096 + soff);
    if (tid < 128) Kreg = ft16[(size_t)b * 4096 + kq * 1024 + 0 * 32 + krw];
    *(v4u*)(smem + 0 * 16384 + sq * 4096 + soff) = Vreg;
    if (tid < 128) *(v4u*)(smem + 32768 + 0 * 2048 + tid * 16) = Kreg;
    __syncthreads();

    int cur = 0;
    for (int s = 0; s < 32; ++s) {
        // issue next step's staging loads (no wait)
        if (s + 1 < 32) {
            Vreg = *(const v4u*)(hv + (size_t)(sq * 32 + s + 1) * 4096 + soff);
            if (tid < 128)
                Kreg = ft16[(size_t)b * 4096 + kq * 1024 + (s + 1) * 32 + krw];
        }

        // compute from buf cur
        const char* vbuf = smem + cur * 16384 + q * 4096;
        const v8s kf = __builtin_bit_cast(v8s,
            *(const v4u*)(smem + 32768 + cur * 2048 + q * 512 + krow * 16));
        const v8s V00 = __builtin_bit_cast(v8s, *(const v4u*)(vbuf + 0 * 1024 + lane * 16));
        const v8s V01 = __builtin_bit_cast(v8s, *(const v4u*)(vbuf + 1 * 1024 + lane * 16));
        const v8s V10 = __builtin_bit_cast(v8s, *(const v4u*)(vbuf + 2 * 1024 + lane * 16));
        const v8s V11 = __builtin_bit_cast(v8s, *(const v4u*)(vbuf + 3 * 1024 + lane * 16));

        v16f z = {0.f,0.f,0.f,0.f,0.f,0.f,0.f,0.f,0.f,0.f,0.f,0.f,0.f,0.f,0.f,0.f};
        v16f sc = __builtin_amdgcn_mfma_f32_32x32x16_bf16(kf, qf, z, 0, 0, 0);
        // after tau: sc[0..7] = P(n_loc=8hh+r), sc[8..15] = n_loc 16..31

        float p[16];
        #pragma unroll
        for (int j = 0; j < 16; ++j) p[j] = __builtin_amdgcn_exp2f(sc[j]);
        #pragma unroll
        for (int j = 0; j < 16; ++j) lsum += p[j];

        v4u a0, a1;
        a0.x = packt(p[0], p[1]);   a0.y = packt(p[2], p[3]);
        a0.z = packt(p[4], p[5]);   a0.w = packt(p[6], p[7]);
        a1.x = packt(p[8], p[9]);   a1.y = packt(p[10], p[11]);
        a1.z = packt(p[12], p[13]); a1.w = packt(p[14], p[15]);
        const v8s pA0 = __builtin_bit_cast(v8s, a0);    // n_loc 0-15
        const v8s pA1 = __builtin_bit_cast(v8s, a1);    // n_loc 16-31

        acc0 = __builtin_amdgcn_mfma_f32_32x32x16_bf16(pA0, V00, acc0, 0, 0, 0);
        acc1 = __builtin_amdgcn_mfma_f32_32x32x16_bf16(pA0, V01, acc1, 0, 0, 0);
        acc0 = __builtin_amdgcn_mfma_f32_32x32x16_bf16(pA1, V10, acc0, 0, 0, 0);
        acc1 = __builtin_amdgcn_mfma_f32_32x32x16_bf16(pA1, V11, acc1, 0, 0, 0);

        // write next step's staging into the other buffer
        if (s + 1 < 32) {
            *(v4u*)(smem + (cur ^ 1) * 16384 + sq * 4096 + soff) = Vreg;
            if (tid < 128) *(v4u*)(smem + 32768 + (cur ^ 1) * 2048 + tid * 16) = Kreg;
        }
        __syncthreads();
        cur ^= 1;
    }

    // fold lane/lane+32 (same m, disjoint n)
    lsum += __shfl_xor(lsum, 32);

    // combine 4 quarters per tile: q0 writes, q1-3 add (aliased over staging)
    if (q == 0) {
        #pragma unroll
        for (int r = 0; r < 16; ++r) {
            const int rowD = (r & 3) + ((r >> 2) << 3) + (hh << 2);
            ldsO[(tile * 32 + rowD) * 65 + l5]      = acc0[r];
            ldsO[(tile * 32 + rowD) * 65 + 32 + l5] = acc1[r];
        }
        if (hh == 0) ldsL[tile * 32 + l5] = lsum;
    }
    __syncthreads();
    #pragma unroll
    for (int ph = 1; ph < 4; ++ph) {
        if (q == ph) {
            #pragma unroll
            for (int r = 0; r < 16; ++r) {
                const int rowD = (r & 3) + ((r >> 2) << 3) + (hh << 2);
                ldsO[(tile * 32 + rowD) * 65 + l5]      += acc0[r];
                ldsO[(tile * 32 + rowD) * 65 + 32 + l5] += acc1[r];
            }
            if (hh == 0) ldsL[tile * 32 + l5] += lsum;
        }
        __syncthreads();
    }

    // final: normalize + gamma*o + x, coalesced over m (128 consecutive)
    const float gam = gamma[0];
    const int m  = tid & 127;
    const int c0 = (tid >> 7) * 8;
    const float rL = 1.0f / ldsL[m];
    #pragma unroll
    for (int k = 0; k < 8; ++k) {
        const int c = c0 + k;
        const float O = ldsO[m * 65 + c];
        const size_t idx = ((size_t)b * 64 + c) * 4096 + m0 + m;
        out[idx] = gam * (O * rL) + x[idx];
    }
}

extern "C" void kernel_launch(void* const* d_in, const int* in_sizes, int n_in,
                              void* d_out, int out_size, void* d_ws, size_t ws_size,
                              hipStream_t stream) {
    const float* x     = (const float*)d_in[0];
    const float* Wq    = (const float*)d_in[1];
    const float* Wk    = (const float*)d_in[2];
    const float* Wv    = (const float*)d_in[3];
    const float* gamma = (const float*)d_in[4];
    float* out = (float*)d_out;

    unsigned int* ftgt = (unsigned int*)d_ws;   // ft 512KB + gt 512KB
    v4u* hswz = (v4u*)(ftgt + 262144);          // 4MB fragment-swizzled h

    hipLaunchKernelGGL(fgh_kernel, dim3(1024), dim3(256), 0, stream,
                       x, Wq, Wk, Wv, ftgt, hswz);
    hipLaunchKernelGGL(attn_kernel, dim3(256), dim3(1024), 0, stream,
                       (const v4u*)ftgt, (const v4u*)(ftgt + 131072),
                       (const char*)hswz, x, gamma, out);
}